// Round 10
// baseline (195.976 us; speedup 1.0000x reference)
//
#include <hip/hip_runtime.h>
#include <cstdint>
#include <cstddef>

#define N_  32
#define C_  64
#define T_  256
#define V_  25
#define R_  8
#define O_  64
#define K_  5
#define NU_ 17
#define U_  25
#define CV  (C_ * V_)        // 1600
#define OG  4                // o's per block
#define NB  (OG * 32)        // 128 ncols

#define OUT_ELEMS ((size_t)N_ * O_ * T_ * V_)   // 13,107,200

typedef __attribute__((ext_vector_type(8))) short bf16x8;
typedef __attribute__((ext_vector_type(4))) float f32x4;

// round-to-nearest-away, 2 ops
static __device__ __forceinline__ unsigned short f2bf(float f) {
    union { float f; unsigned u; } c; c.f = f;
    return (unsigned short)((c.u + 0x8000u) >> 16);
}
static __device__ __forceinline__ float bf2f(unsigned short h) {
    union { unsigned u; float f; } c; c.u = ((unsigned)h) << 16; return c.f;
}
static __device__ __forceinline__ float bf_lo(unsigned d) {
    union { unsigned u; float f; } c; c.u = d << 16; return c.f;
}
static __device__ __forceinline__ float bf_hi(unsigned d) {
    union { unsigned u; float f; } c; c.u = d & 0xFFFF0000u; return c.f;
}
static __device__ __forceinline__ unsigned pk2(float a, float b) {
    union { float f; unsigned u; } ca, cb; ca.f = a; cb.f = b;
    return ((ca.u + 0x8000u) >> 16) | ((cb.u + 0x8000u) & 0xFFFF0000u);
}

// ---------------------------------------------------------------------------
// k_xcast: fragment-native xT3 with cv' = v*64+c ordering:
//   xT3[n][tt(16)][s'(200)][tl(16)][ke(8)],  s' = v*8 + c/8, ke = c&7.
// Vectorized float4 input pass; flat per-c tile [c][t*25+v].
// Also per-t-block partial pool sums pp[n][tb][c*25+v].
// ---------------------------------------------------------------------------
__global__ void k_xcast(const float* __restrict__ x, unsigned short* __restrict__ xT3,
                        float* __restrict__ pp) {
    __shared__ unsigned short tile[C_][408];   // [c][t*25+v], row 816 B
    int bid = blockIdx.x;
    int n = bid >> 4, tb = bid & 15;
    int tid = threadIdx.x;
    const float* xb = x + (size_t)n * C_ * T_ * V_ + tb * 400;
#pragma unroll
    for (int it = 0; it < 25; ++it) {
        int i = it * 256 + tid;          // < 6400
        int c = i / 100, q = i - c * 100;
        float4 v4 = *(const float4*)(xb + (size_t)c * (T_ * V_) + q * 4);
        uint2 w;
        w.x = pk2(v4.x, v4.y);
        w.y = pk2(v4.z, v4.w);
        *(uint2*)&tile[c][q * 4] = w;
    }
    __syncthreads();
    unsigned short* dstb = xT3 + ((size_t)(n * 16 + tb) * 200) * 128;
    for (int i = tid; i < 200 * 16; i += 256) {
        int sp = i >> 4, tl = i & 15;
        int v = sp >> 3, c0 = (sp & 7) * 8;
        unsigned short h[8];
#pragma unroll
        for (int j = 0; j < 8; ++j) h[j] = tile[c0 + j][tl * 25 + v];
        uint4 pk;
        pk.x = (unsigned)h[0] | ((unsigned)h[1] << 16);
        pk.y = (unsigned)h[2] | ((unsigned)h[3] << 16);
        pk.z = (unsigned)h[4] | ((unsigned)h[5] << 16);
        pk.w = (unsigned)h[6] | ((unsigned)h[7] << 16);
        *(uint4*)(dstb + (size_t)sp * 128 + tl * 8) = pk;
    }
    float* ppd = pp + ((size_t)n * 16 + tb) * CV;
    for (int e = tid; e < CV; e += 256) {
        int c = e / 25, v = e - c * 25;
        float s = 0.f;
#pragma unroll
        for (int t = 0; t < 16; ++t) s += bf2f(tile[c][t * 25 + v]);
        ppd[e] = s;
    }
}

// classic pool (slow tier)
__global__ void k_pool(const float* __restrict__ x, float* __restrict__ pool) {
    int nc = blockIdx.x;
    int t  = threadIdx.x;
    const float* px = x + ((size_t)nc * T_ + t) * V_;
    float acc[V_];
#pragma unroll
    for (int v = 0; v < V_; ++v) acc[v] = px[v];
#pragma unroll
    for (int off = 32; off > 0; off >>= 1) {
#pragma unroll
        for (int v = 0; v < V_; ++v) acc[v] += __shfl_down(acc[v], off, 64);
    }
    __shared__ float sm[4][V_];
    int wave = t >> 6, lane = t & 63;
    if (lane == 0) {
#pragma unroll
        for (int v = 0; v < V_; ++v) sm[wave][v] = acc[v];
    }
    __syncthreads();
    if (t < V_) {
        float s = sm[0][t] + sm[1][t] + sm[2][t] + sm[3][t];
        pool[(size_t)nc * V_ + t] = s * (1.0f / T_);
    }
}

// ---------------------------------------------------------------------------
// k_tvals (slow tier only)
// ---------------------------------------------------------------------------
__global__ void k_tvals(const float* __restrict__ pool,
                        const float* __restrict__ W11, const float* __restrict__ b11,
                        const float* __restrict__ W12, const float* __restrict__ b12,
                        const float* __restrict__ W2,  const float* __restrict__ b2,
                        float* __restrict__ t2o, float* __restrict__ tSo) {
    int kn = blockIdx.x;
    int k = kn / N_, n = kn % N_;
    int tid = threadIdx.x;
    int r = tid >> 5, v = tid & 31;
    if (v >= V_) return;
    const float* pp = pool + (size_t)n * C_ * V_ + v;
    const float* w2 = W2 + ((size_t)k * R_ + r) * C_;
    const float* w1 = ((v < NU_) ? W11 : W12) + ((size_t)k * R_ + r) * C_;
    float a2 = b2[k * R_ + r];
    float a1 = (v < NU_) ? b11[k * R_ + r] : b12[k * R_ + r];
    for (int c = 0; c < C_; ++c) {
        float p = pp[(size_t)c * V_];
        a2 += w2[c] * p;
        a1 += w1[c] * p;
    }
    size_t idx = (((size_t)k * N_ + n) * R_ + r) * V_ + v;
    t2o[idx] = a2;
    tSo[idx] = a1;
}

// ---------------------------------------------------------------------------
// k_graphs (slow tier)
// ---------------------------------------------------------------------------
__global__ void k_graphs(const float* __restrict__ t2v, const float* __restrict__ tSv,
                         const float* __restrict__ W4, const float* __restrict__ b4,
                         float* __restrict__ graphs) {
    int kn = blockIdx.x;
    int k = kn / N_, n = kn % N_;
    int kup = (k + 1) % K_;
    __shared__ float F[R_][V_ * V_];
    __shared__ float w4s[O_][R_];
    __shared__ float b4s[O_];
    int tid = threadIdx.x;
    for (int i = tid; i < O_ * R_; i += 256) w4s[i / R_][i % R_] = W4[(size_t)k * O_ * R_ + i];
    if (tid < O_) b4s[tid] = b4[k * O_ + tid];
    for (int idx = tid; idx < R_ * V_ * V_; idx += 256) {
        int r = idx / (V_ * V_), uv = idx % (V_ * V_);
        int u = uv / V_, v = uv % V_;
        int ks = (u < NU_) ? kup : k;
        size_t base = (((size_t)ks * N_ + n) * R_ + r) * V_;
        F[r][uv] = tanhf(tSv[base + u] - t2v[base + v]);
    }
    __syncthreads();
    float* gout = graphs + ((size_t)k * N_ + n) * O_ * (V_ * V_);
    for (int idx = tid; idx < O_ * V_ * V_; idx += 256) {
        int o = idx / (V_ * V_), uv = idx % (V_ * V_);
        float a = b4s[o];
#pragma unroll
        for (int r = 0; r < R_; ++r) a += w4s[o][r] * F[r][uv];
        gout[idx] = a;
    }
}

// ---------------------------------------------------------------------------
// k_graphs2b (fast tier): pool-from-pp + tvals (k and kup) + F + graphs, fused.
// ---------------------------------------------------------------------------
__global__ void k_graphs2b(const float* __restrict__ pp,
                           const float* __restrict__ W11, const float* __restrict__ b11,
                           const float* __restrict__ W12, const float* __restrict__ b12,
                           const float* __restrict__ W2,  const float* __restrict__ b2,
                           const float* __restrict__ W4,  const float* __restrict__ b4,
                           float* __restrict__ graphs) {
    int kn = blockIdx.x;
    int k = kn / N_, n = kn % N_;
    int kup = (k + 1) % K_;
    __shared__ float poolL[CV];        // 6.4 KB
    __shared__ float t2s[2][R_][V_];
    __shared__ float tSs[2][R_][V_];
    __shared__ float F[R_][V_ * V_];
    __shared__ float w4s[O_][R_];
    __shared__ float b4s[O_];
    int tid = threadIdx.x;
    for (int i = tid; i < O_ * R_; i += 512) w4s[i / R_][i % R_] = W4[(size_t)k * O_ * R_ + i];
    if (tid < O_) b4s[tid] = b4[k * O_ + tid];
    const float* ppn = pp + (size_t)n * 16 * CV;
    for (int i = tid; i < CV; i += 512) {
        float s = 0.f;
#pragma unroll
        for (int tb = 0; tb < 16; ++tb) s += ppn[(size_t)tb * CV + i];
        poolL[i] = s * (1.0f / T_);
    }
    __syncthreads();
    for (int i = tid; i < 2 * R_ * V_; i += 512) {
        int ks = i / (R_ * V_);
        int rem = i - ks * (R_ * V_);
        int r = rem / V_, v = rem - r * V_;
        int kk = ks ? kup : k;
        const float* w2 = W2 + ((size_t)kk * R_ + r) * C_;
        const float* w1 = ((v < NU_) ? W11 : W12) + ((size_t)kk * R_ + r) * C_;
        float a2 = b2[kk * R_ + r];
        float a1 = (v < NU_) ? b11[kk * R_ + r] : b12[kk * R_ + r];
        for (int c = 0; c < C_; ++c) {
            float p = poolL[c * 25 + v];
            a2 += w2[c] * p;
            a1 += w1[c] * p;
        }
        t2s[ks][r][v] = a2;
        tSs[ks][r][v] = a1;
    }
    __syncthreads();
    for (int idx = tid; idx < R_ * V_ * V_; idx += 512) {
        int r = idx / (V_ * V_), uv = idx % (V_ * V_);
        int u = uv / V_, v = uv % V_;
        int ks = (u < NU_) ? 1 : 0;
        F[r][uv] = tanhf(tSs[ks][r][u] - t2s[ks][r][v]);
    }
    __syncthreads();
    float* gout = graphs + ((size_t)k * N_ + n) * O_ * (V_ * V_);
    for (int idx = tid; idx < O_ * V_ * V_; idx += 512) {
        int o = idx / (V_ * V_), uv = idx % (V_ * V_);
        float a = b4s[o];
#pragma unroll
        for (int r = 0; r < R_; ++r) a += w4s[o][r] * F[r][uv];
        gout[idx] = a;
    }
}

// ---------------------------------------------------------------------------
// k_main_fast: per (n, 4-o group) GEMM over cv'=v*64+c; A from global (xT3).
// K-loop runs in PAIRS of chunks sharing the same c-half (parity):
//   pair i (i<24): par=i&1, v∈{(i>>1)*2, +1}; i=24/25: v=24 single, par=i&1.
// h_form_pair: 10 W3 b128 reads SHARED across the pair's 2 chunks,
//   per-v G read = 1 b64 + 1 b16 (bf16 G), 1 b128 Hs write per v.
// Hs has 4 chunk-slots (32 KB): pair i occupies slots {2*(i&1), +1}.
// G stored bf16 (Gbf4 uint2 k0..3 + Gbf1 k4) -> LDS 63 KB, 2 blocks/CU.
// NOTE: register file at the 2-blocks/CU cliff (64 VGPR + 64 acc) — don't
// add persistent register state.
// ---------------------------------------------------------------------------
__global__ __launch_bounds__(512, 4) void k_main_fast(
    const unsigned short* __restrict__ xT3,  // [N][16][200][16][8] bf16 bits
    const float* __restrict__ graphs,        // [K][N][O][625]
    const float* __restrict__ Adj,           // [K][625]
    const float* __restrict__ W3,            // [K][O][C]
    const float* __restrict__ b3,            // [K][O]
    float* __restrict__ out) {

    __shared__ unsigned short Hs[4][4][NB][8];   // 32 KB (4 chunk-slots)
    __shared__ uint2 Gbf4[OG * 625];             // 20 KB (bf16 k0..3), idx o*625+v*25+u
    __shared__ unsigned short Gbf1[OG * 625];    //  5 KB (bf16 k4)
    __shared__ f32x4 W3km[K_ * OG * 16];         //  5 KB: [k][o][c], f32x4 over c
    __shared__ float biasS[NB];                  // 512 B

    const int tid = threadIdx.x;
    const int bid = blockIdx.x;
    const int obase = (bid & 15) * OG;
    const int n = bid >> 4;
    const int lane = tid & 63;
    const int wv_ = tid >> 6;

    // ---- stage G as bf16 (graphs + Adj) ----
    const size_t kstride = (size_t)N_ * O_ * 625;
    for (int i = tid; i < OG * 625; i += 512) {
        int o = i / 625, uv = i - o * 625;
        int u = uv / 25, v = uv - u * 25;
        size_t gb = ((size_t)n * O_ + obase + o) * 625 + uv;
        float g0 = graphs[gb]               + Adj[uv];
        float g1 = graphs[gb + kstride]     + Adj[625 + uv];
        float g2 = graphs[gb + 2 * kstride] + Adj[1250 + uv];
        float g3 = graphs[gb + 3 * kstride] + Adj[1875 + uv];
        float g4 = graphs[gb + 4 * kstride] + Adj[2500 + uv];
        int idx = o * 625 + v * 25 + u;
        uint2 w; w.x = pk2(g0, g1); w.y = pk2(g2, g3);
        Gbf4[idx] = w;
        Gbf1[idx] = f2bf(g4);
    }
    // ---- stage W3 k-major (fp32) ----
    for (int i = tid; i < K_ * OG * C_; i += 512) {   // 1280 scalars
        int k = i / (OG * C_);
        int rem = i - k * (OG * C_);
        int o = rem >> 6, c = rem & 63;
        ((float*)W3km)[((k * OG + o) * C_) + c] = W3[((size_t)k * O_ + obase + o) * C_ + c];
    }
    __syncthreads();

    // ---- in-block bias ----
    if (tid < NB) {
        int o = tid >> 5, u = tid & 31;
        float bv = 0.f;
        if (u < U_) {
            float s0 = 0.f, s1 = 0.f, s2 = 0.f, s3 = 0.f, s4 = 0.f;
            for (int v = 0; v < V_; ++v) {
                int idx = o * 625 + v * 25 + u;
                uint2 w = Gbf4[idx];
                s0 += bf_lo(w.x); s1 += bf_hi(w.x);
                s2 += bf_lo(w.y); s3 += bf_hi(w.y);
                s4 += bf2f(Gbf1[idx]);
            }
            bv = s0 * b3[0 * O_ + obase + o] + s1 * b3[1 * O_ + obase + o]
               + s2 * b3[2 * O_ + obase + o] + s3 * b3[3 * O_ + obase + o]
               + s4 * b3[4 * O_ + obase + o];
        }
        biasS[tid] = bv;
    }

    // ---- H_FORM (pairwise) ----
    const int sl = wv_ & 3;
    const int hncol = (wv_ >> 2) * 64 + lane;   // 0..127
    const int ho = hncol >> 5;
    const int hu = hncol & 31;
    const int kw = OG * 16;                     // f32x4 stride per k in W3km
    auto h_form_pair = [&](int i) {
        const int par = i & 1;
        const int vb  = (i < 24) ? ((i >> 1) * 2) : 24;
        const int nv  = (i < 24) ? 2 : 1;
        const int csb = (i & 1) * 2;
        const int c0  = par * 32 + sl * 8;
        const f32x4* wb = &W3km[(ho * 16) + (c0 >> 2)];
        f32x4 w0a = wb[0],        w0b = wb[1];
        f32x4 w1a = wb[kw],       w1b = wb[kw + 1];
        f32x4 w2a = wb[2 * kw],   w2b = wb[2 * kw + 1];
        f32x4 w3a = wb[3 * kw],   w3b = wb[3 * kw + 1];
        f32x4 w4a = wb[4 * kw],   w4b = wb[4 * kw + 1];
        for (int vi = 0; vi < nv; ++vi) {
            const int v = vb + vi;
            float g0 = 0.f, g1 = 0.f, g2 = 0.f, g3 = 0.f, g4 = 0.f;
            if (hu < U_) {
                int gi = ho * 625 + v * 25 + hu;
                uint2 gw = Gbf4[gi];
                g0 = bf_lo(gw.x); g1 = bf_hi(gw.x);
                g2 = bf_lo(gw.y); g3 = bf_hi(gw.y);
                g4 = bf2f(Gbf1[gi]);
            }
            float h[8];
#pragma unroll
            for (int j = 0; j < 4; ++j) {
                h[j]     = w0a[j] * g0 + w1a[j] * g1 + w2a[j] * g2 + w3a[j] * g3 + w4a[j] * g4;
                h[4 + j] = w0b[j] * g0 + w1b[j] * g1 + w2b[j] * g2 + w3b[j] * g3 + w4b[j] * g4;
            }
            uint4 hv;
            hv.x = pk2(h[0], h[1]); hv.y = pk2(h[2], h[3]);
            hv.z = pk2(h[4], h[5]); hv.w = pk2(h[6], h[7]);
            *(uint4*)&Hs[csb + vi][sl][hncol][0] = hv;
        }
    };

    // ---- MFMA wave grid ----
    const int wm = wv_ >> 1;            // 0..3 -> t-base wm*64
    const int wn = wv_ & 1;             // 0..1 -> ncol-base wn*64
    const int lr = lane & 15;
    const int eg = lane >> 4;

    f32x4 acc[4][4];
#pragma unroll
    for (int mt = 0; mt < 4; ++mt)
#pragma unroll
        for (int nt = 0; nt < 4; ++nt) acc[mt][nt] = (f32x4){0.f, 0.f, 0.f, 0.f};

    const unsigned short* An = xT3 + (size_t)n * (T_ * CV);

    auto consume = [&](int v, int par, int cs) {
        uint4 av[4];
#pragma unroll
        for (int mt = 0; mt < 4; ++mt) {
            int tt = wm * 4 + mt;
            av[mt] = *(const uint4*)(An + ((size_t)(tt * 200 + v * 8 + par * 4 + eg)) * 128 + lr * 8);
        }
        bf16x8 b[4];
#pragma unroll
        for (int nt = 0; nt < 4; ++nt)
            b[nt] = *(const bf16x8*)&Hs[cs][eg][wn * 64 + nt * 16 + lr][0];
        __builtin_amdgcn_s_setprio(1);
#pragma unroll
        for (int mt = 0; mt < 4; ++mt) {
            bf16x8 a;
            { union { uint4 u; bf16x8 h; } cvt; cvt.u = av[mt]; a = cvt.h; }
#pragma unroll
            for (int nt = 0; nt < 4; ++nt)
                acc[mt][nt] = __builtin_amdgcn_mfma_f32_16x16x32_bf16(a, b[nt], acc[mt][nt], 0, 0, 0);
        }
        __builtin_amdgcn_s_setprio(0);
    };

    h_form_pair(0);
    __syncthreads();

    for (int i = 0; i < 26; ++i) {
        const int par = i & 1;
        const int vb  = (i < 24) ? ((i >> 1) * 2) : 24;
        const int nv  = (i < 24) ? 2 : 1;
        const int csb = (i & 1) * 2;
        consume(vb, par, csb);
        if (nv == 2) consume(vb + 1, par, csb + 1);
        if (i + 1 < 26) h_form_pair(i + 1);
        __syncthreads();
    }

    // ---- epilogue: C/D col = lane&15 (ncol), row = eg*4 + r2 (t) ----
#pragma unroll
    for (int nt = 0; nt < 4; ++nt) {
        int ncol = wn * 64 + nt * 16 + lr;
        int ol = ncol >> 5;
        int u  = ncol & 31;
        if (u < U_) {
            float bv = biasS[ncol];
            float* ob = out + ((size_t)n * O_ + obase + ol) * T_ * V_ + u;
#pragma unroll
            for (int mt = 0; mt < 4; ++mt) {
                int t0 = wm * 64 + mt * 16 + eg * 4;
#pragma unroll
                for (int r2 = 0; r2 < 4; ++r2)
                    ob[(size_t)(t0 + r2) * V_] = acc[mt][nt][r2] + bv;
            }
        }
    }
}

// ---------------------------------------------------------------------------
// k_main_slow (fallback, proven R2 path)
// ---------------------------------------------------------------------------
#define OB 4
#define TB 64
__global__ __launch_bounds__(256, 1) void k_main_slow(
    const float* __restrict__ x, const float* __restrict__ graphs,
    const float* __restrict__ A, const float* __restrict__ W3,
    const float* __restrict__ b3, float* __restrict__ out) {
    int bid = blockIdx.x;
    int tb = bid & 3;
    int ob = (bid >> 2) & 15;
    int n  = bid >> 6;
    int tid = threadIdx.x;
    int ol = tid >> 6;
    int tl = tid & 63;
    int t = tb * TB + tl;
    int o = ob * OB + ol;

    __shared__ float Gs[K_][OB][V_][28];
    __shared__ float W3s[K_][OB][C_];
    __shared__ float b3s[K_][OB];

    for (int i = tid; i < K_ * OB * V_ * V_; i += 256) {
        int k   = i / (OB * V_ * V_);
        int rem = i % (OB * V_ * V_);
        int oo  = rem / (V_ * V_);
        int uv  = rem % (V_ * V_);
        Gs[k][oo][uv / V_][uv % V_] =
            graphs[(((size_t)k * N_ + n) * O_ + ob * OB + oo) * (V_ * V_) + uv]
            + A[k * V_ * V_ + uv];
    }
    for (int i = tid; i < K_ * OB * C_; i += 256) {
        int k   = i / (OB * C_);
        int rem = i % (OB * C_);
        int oo  = rem / C_, c = rem % C_;
        W3s[k][oo][c] = W3[((size_t)k * O_ + ob * OB + oo) * C_ + c];
    }
    if (tid < K_ * OB) b3s[tid / OB][tid % OB] = b3[(tid / OB) * O_ + ob * OB + tid % OB];
    __syncthreads();

    float x2[K_][V_];
#pragma unroll
    for (int k = 0; k < K_; ++k)
#pragma unroll
        for (int v = 0; v < V_; ++v) x2[k][v] = b3s[k][ol];

    const float* xb = x + ((size_t)n * C_ * T_ + t) * V_;
    for (int c = 0; c < C_; ++c) {
        const float* p = xb + (size_t)c * T_ * V_;
        float xv[V_];
#pragma unroll
        for (int v = 0; v < V_; ++v) xv[v] = p[v];
#pragma unroll
        for (int k = 0; k < K_; ++k) {
            float w = W3s[k][ol][c];
#pragma unroll
            for (int v = 0; v < V_; ++v) x2[k][v] += w * xv[v];
        }
    }

    float acc[V_];
#pragma unroll
    for (int u = 0; u < V_; ++u) acc[u] = 0.0f;
#pragma unroll
    for (int k = 0; k < K_; ++k) {
#pragma unroll
        for (int u = 0; u < V_; ++u) {
            const float* gr = &Gs[k][ol][u][0];
            float s = 0.0f;
#pragma unroll
            for (int v = 0; v < V_; ++v) s += gr[v] * x2[k][v];
            acc[u] += s;
        }
    }
    float* po = out + (((size_t)n * O_ + o) * T_ + t) * V_;
#pragma unroll
    for (int u = 0; u < V_; ++u) po[u] = acc[u];
}

// ---------------------------------------------------------------------------
extern "C" void kernel_launch(void* const* d_in, const int* in_sizes, int n_in,
                              void* d_out, int out_size, void* d_ws, size_t ws_size,
                              hipStream_t stream) {
    const float* x   = (const float*)d_in[0];
    const float* A   = (const float*)d_in[1];
    const float* W11 = (const float*)d_in[2];
    const float* b11 = (const float*)d_in[3];
    const float* W12 = (const float*)d_in[4];
    const float* b12 = (const float*)d_in[5];
    const float* W2  = (const float*)d_in[6];
    const float* b2  = (const float*)d_in[7];
    const float* W3  = (const float*)d_in[8];
    const float* b3  = (const float*)d_in[9];
    const float* W4  = (const float*)d_in[10];
    const float* b4  = (const float*)d_in[11];

    float* out    = (float*)d_out;
    float* graphs = out + OUT_ELEMS;   // second tuple element

    const size_t xT_bytes = sizeof(unsigned short) * (size_t)N_ * T_ * CV;  // 26.2 MB
    const size_t pp_bytes = sizeof(float) * (size_t)N_ * 16 * CV;           //  3.3 MB
    const size_t hdr      = (size_t)(1 << 20);
    const bool fast = (ws_size >= hdr + xT_bytes + pp_bytes);

    const size_t poolElems = (size_t)N_ * C_ * V_;      // 51,200
    const size_t tElems    = (size_t)K_ * N_ * R_ * V_; // 32,000
    const size_t slowNeed  = (poolElems + 2 * tElems) * sizeof(float);

    float* scratch = (fast || ws_size >= slowNeed) ? (float*)d_ws : out;
    float* pool = scratch;
    float* t2v  = scratch + poolElems;
    float* tSv  = t2v + tElems;
    unsigned short* xT3 = (unsigned short*)((char*)d_ws + hdr);
    float* pp = (float*)((char*)d_ws + hdr + xT_bytes);

    if (fast) {
        k_xcast   <<<N_ * 16, 256, 0, stream>>>(x, xT3, pp);
        k_graphs2b<<<K_ * N_, 512, 0, stream>>>(pp, W11, b11, W12, b12, W2, b2, W4, b4, graphs);
        k_main_fast<<<N_ * 16, 512, 0, stream>>>(xT3, graphs, A, W3, b3, out);
    } else {
        k_pool  <<<N_ * C_, 256, 0, stream>>>(x, pool);
        k_tvals <<<K_ * N_, 256, 0, stream>>>(pool, W11, b11, W12, b12, W2, b2, t2v, tSv);
        k_graphs<<<K_ * N_, 256, 0, stream>>>(t2v, tSv, W4, b4, graphs);
        k_main_slow<<<N_ * (O_ / OB) * 4, 256, 0, stream>>>(x, graphs, A, W3, b3, out);
    }
}

// Round 11
// 110.899 us; speedup vs baseline: 1.7672x; 1.7672x over previous
//
#include <hip/hip_runtime.h>
#include <cstdint>
#include <cstddef>

#define N_  32
#define C_  64
#define T_  256
#define V_  25
#define R_  8
#define O_  64
#define K_  5
#define NU_ 17
#define U_  25
#define CV  (C_ * V_)        // 1600
#define OG  4                // o's per block
#define NB  (OG * 32)        // 128 ncols

#define OUT_ELEMS ((size_t)N_ * O_ * T_ * V_)   // 13,107,200

typedef __attribute__((ext_vector_type(8))) short bf16x8;
typedef __attribute__((ext_vector_type(4))) float f32x4;

// round-to-nearest-away, 2 ops
static __device__ __forceinline__ unsigned short f2bf(float f) {
    union { float f; unsigned u; } c; c.f = f;
    return (unsigned short)((c.u + 0x8000u) >> 16);
}
static __device__ __forceinline__ float bf2f(unsigned short h) {
    union { unsigned u; float f; } c; c.u = ((unsigned)h) << 16; return c.f;
}
static __device__ __forceinline__ unsigned pk2(float a, float b) {
    union { float f; unsigned u; } ca, cb; ca.f = a; cb.f = b;
    return ((ca.u + 0x8000u) >> 16) | ((cb.u + 0x8000u) & 0xFFFF0000u);
}
// single-instruction packed f32->bf16 (RNE); gfx950 has no builtin (T12/m240)
static __device__ __forceinline__ unsigned cvtpk(float a, float b) {
    unsigned r;
    asm("v_cvt_pk_bf16_f32 %0, %1, %2" : "=v"(r) : "v"(a), "v"(b));
    return r;
}

// ---------------------------------------------------------------------------
// k_xcast: fragment-native xT3 with cv' = v*64+c ordering:
//   xT3[n][tt(16)][s'(200)][tl(16)][ke(8)],  s' = v*8 + c/8, ke = c&7.
// ---------------------------------------------------------------------------
__global__ void k_xcast(const float* __restrict__ x, unsigned short* __restrict__ xT3,
                        float* __restrict__ pp) {
    __shared__ unsigned short tile[C_][408];   // [c][t*25+v], row 816 B
    int bid = blockIdx.x;
    int n = bid >> 4, tb = bid & 15;
    int tid = threadIdx.x;
    const float* xb = x + (size_t)n * C_ * T_ * V_ + tb * 400;
#pragma unroll
    for (int it = 0; it < 25; ++it) {
        int i = it * 256 + tid;          // < 6400
        int c = i / 100, q = i - c * 100;
        float4 v4 = *(const float4*)(xb + (size_t)c * (T_ * V_) + q * 4);
        uint2 w;
        w.x = pk2(v4.x, v4.y);
        w.y = pk2(v4.z, v4.w);
        *(uint2*)&tile[c][q * 4] = w;
    }
    __syncthreads();
    unsigned short* dstb = xT3 + ((size_t)(n * 16 + tb) * 200) * 128;
    for (int i = tid; i < 200 * 16; i += 256) {
        int sp = i >> 4, tl = i & 15;
        int v = sp >> 3, c0 = (sp & 7) * 8;
        unsigned short h[8];
#pragma unroll
        for (int j = 0; j < 8; ++j) h[j] = tile[c0 + j][tl * 25 + v];
        uint4 pk;
        pk.x = (unsigned)h[0] | ((unsigned)h[1] << 16);
        pk.y = (unsigned)h[2] | ((unsigned)h[3] << 16);
        pk.z = (unsigned)h[4] | ((unsigned)h[5] << 16);
        pk.w = (unsigned)h[6] | ((unsigned)h[7] << 16);
        *(uint4*)(dstb + (size_t)sp * 128 + tl * 8) = pk;
    }
    float* ppd = pp + ((size_t)n * 16 + tb) * CV;
    for (int e = tid; e < CV; e += 256) {
        int c = e / 25, v = e - c * 25;
        float s = 0.f;
#pragma unroll
        for (int t = 0; t < 16; ++t) s += bf2f(tile[c][t * 25 + v]);
        ppd[e] = s;
    }
}

// classic pool (slow tier)
__global__ void k_pool(const float* __restrict__ x, float* __restrict__ pool) {
    int nc = blockIdx.x;
    int t  = threadIdx.x;
    const float* px = x + ((size_t)nc * T_ + t) * V_;
    float acc[V_];
#pragma unroll
    for (int v = 0; v < V_; ++v) acc[v] = px[v];
#pragma unroll
    for (int off = 32; off > 0; off >>= 1) {
#pragma unroll
        for (int v = 0; v < V_; ++v) acc[v] += __shfl_down(acc[v], off, 64);
    }
    __shared__ float sm[4][V_];
    int wave = t >> 6, lane = t & 63;
    if (lane == 0) {
#pragma unroll
        for (int v = 0; v < V_; ++v) sm[wave][v] = acc[v];
    }
    __syncthreads();
    if (t < V_) {
        float s = sm[0][t] + sm[1][t] + sm[2][t] + sm[3][t];
        pool[(size_t)nc * V_ + t] = s * (1.0f / T_);
    }
}

// ---------------------------------------------------------------------------
// k_tvals (slow tier only)
// ---------------------------------------------------------------------------
__global__ void k_tvals(const float* __restrict__ pool,
                        const float* __restrict__ W11, const float* __restrict__ b11,
                        const float* __restrict__ W12, const float* __restrict__ b12,
                        const float* __restrict__ W2,  const float* __restrict__ b2,
                        float* __restrict__ t2o, float* __restrict__ tSo) {
    int kn = blockIdx.x;
    int k = kn / N_, n = kn % N_;
    int tid = threadIdx.x;
    int r = tid >> 5, v = tid & 31;
    if (v >= V_) return;
    const float* pp = pool + (size_t)n * C_ * V_ + v;
    const float* w2 = W2 + ((size_t)k * R_ + r) * C_;
    const float* w1 = ((v < NU_) ? W11 : W12) + ((size_t)k * R_ + r) * C_;
    float a2 = b2[k * R_ + r];
    float a1 = (v < NU_) ? b11[k * R_ + r] : b12[k * R_ + r];
    for (int c = 0; c < C_; ++c) {
        float p = pp[(size_t)c * V_];
        a2 += w2[c] * p;
        a1 += w1[c] * p;
    }
    size_t idx = (((size_t)k * N_ + n) * R_ + r) * V_ + v;
    t2o[idx] = a2;
    tSo[idx] = a1;
}

// ---------------------------------------------------------------------------
// k_graphs (slow tier)
// ---------------------------------------------------------------------------
__global__ void k_graphs(const float* __restrict__ t2v, const float* __restrict__ tSv,
                         const float* __restrict__ W4, const float* __restrict__ b4,
                         float* __restrict__ graphs) {
    int kn = blockIdx.x;
    int k = kn / N_, n = kn % N_;
    int kup = (k + 1) % K_;
    __shared__ float F[R_][V_ * V_];
    __shared__ float w4s[O_][R_];
    __shared__ float b4s[O_];
    int tid = threadIdx.x;
    for (int i = tid; i < O_ * R_; i += 256) w4s[i / R_][i % R_] = W4[(size_t)k * O_ * R_ + i];
    if (tid < O_) b4s[tid] = b4[k * O_ + tid];
    for (int idx = tid; idx < R_ * V_ * V_; idx += 256) {
        int r = idx / (V_ * V_), uv = idx % (V_ * V_);
        int u = uv / V_, v = uv % V_;
        int ks = (u < NU_) ? kup : k;
        size_t base = (((size_t)ks * N_ + n) * R_ + r) * V_;
        F[r][uv] = tanhf(tSv[base + u] - t2v[base + v]);
    }
    __syncthreads();
    float* gout = graphs + ((size_t)k * N_ + n) * O_ * (V_ * V_);
    for (int idx = tid; idx < O_ * V_ * V_; idx += 256) {
        int o = idx / (V_ * V_), uv = idx % (V_ * V_);
        float a = b4s[o];
#pragma unroll
        for (int r = 0; r < R_; ++r) a += w4s[o][r] * F[r][uv];
        gout[idx] = a;
    }
}

// ---------------------------------------------------------------------------
// k_graphs2c (fast tier): pool-from-pp + tvals + F + graphs, fused; split
// over 2 o-halves for occupancy (320 blocks instead of 160).
// ---------------------------------------------------------------------------
__global__ void k_graphs2c(const float* __restrict__ pp,
                           const float* __restrict__ W11, const float* __restrict__ b11,
                           const float* __restrict__ W12, const float* __restrict__ b12,
                           const float* __restrict__ W2,  const float* __restrict__ b2,
                           const float* __restrict__ W4,  const float* __restrict__ b4,
                           float* __restrict__ graphs) {
    int bid = blockIdx.x;
    int og = bid & 1;
    int kn = bid >> 1;
    int k = kn / N_, n = kn % N_;
    int kup = (k + 1) % K_;
    __shared__ float poolL[CV];        // 6.4 KB
    __shared__ float t2s[2][R_][V_];
    __shared__ float tSs[2][R_][V_];
    __shared__ float F[R_][V_ * V_];
    __shared__ float w4s[O_][R_];
    __shared__ float b4s[O_];
    int tid = threadIdx.x;
    for (int i = tid; i < O_ * R_; i += 512) w4s[i / R_][i % R_] = W4[(size_t)k * O_ * R_ + i];
    if (tid < O_) b4s[tid] = b4[k * O_ + tid];
    const float* ppn = pp + (size_t)n * 16 * CV;
    for (int i = tid; i < CV; i += 512) {
        float s = 0.f;
#pragma unroll
        for (int tb = 0; tb < 16; ++tb) s += ppn[(size_t)tb * CV + i];
        poolL[i] = s * (1.0f / T_);
    }
    __syncthreads();
    for (int i = tid; i < 2 * R_ * V_; i += 512) {
        int ks = i / (R_ * V_);
        int rem = i - ks * (R_ * V_);
        int r = rem / V_, v = rem - r * V_;
        int kk = ks ? kup : k;
        const float* w2 = W2 + ((size_t)kk * R_ + r) * C_;
        const float* w1 = ((v < NU_) ? W11 : W12) + ((size_t)kk * R_ + r) * C_;
        float a2 = b2[kk * R_ + r];
        float a1 = (v < NU_) ? b11[kk * R_ + r] : b12[kk * R_ + r];
        for (int c = 0; c < C_; ++c) {
            float p = poolL[c * 25 + v];
            a2 += w2[c] * p;
            a1 += w1[c] * p;
        }
        t2s[ks][r][v] = a2;
        tSs[ks][r][v] = a1;
    }
    __syncthreads();
    for (int idx = tid; idx < R_ * V_ * V_; idx += 512) {
        int r = idx / (V_ * V_), uv = idx % (V_ * V_);
        int u = uv / V_, v = uv % V_;
        int ks = (u < NU_) ? 1 : 0;
        F[r][uv] = tanhf(tSs[ks][r][u] - t2s[ks][r][v]);
    }
    __syncthreads();
    float* gout = graphs + ((size_t)k * N_ + n) * O_ * (V_ * V_);
    const int half = O_ * V_ * V_ / 2;           // 20000
    for (int idx = og * half + tid; idx < (og + 1) * half; idx += 512) {
        int o = idx / (V_ * V_), uv = idx % (V_ * V_);
        float a = b4s[o];
#pragma unroll
        for (int r = 0; r < R_; ++r) a += w4s[o][r] * F[r][uv];
        gout[idx] = a;
    }
}

// ---------------------------------------------------------------------------
// k_main_fast: R7 schedule, pair-unrolled (chunks 2i,2i+1 share v):
//  - all LDS addresses are static offsets from per-thread bases
//  - A pointers advance by a constant (1024 elems) once per pair
//  - G read once per pair (g carried in 5 regs)
//  - v_cvt_pk_bf16_f32 for the H pack
// Barrier structure and register shape IDENTICAL to the proven R7 version.
// Register file is at the 2-blocks/CU cliff (64 VGPR + 64 acc) — watch
// WRITE_SIZE for spill regressions.
// ---------------------------------------------------------------------------
__global__ __launch_bounds__(512, 4) void k_main_fast(
    const unsigned short* __restrict__ xT3,  // [N][16][200][16][8] bf16 bits
    const float* __restrict__ graphs,        // [K][N][O][625]
    const float* __restrict__ Adj,           // [K][625]
    const float* __restrict__ W3,            // [K][O][C]
    const float* __restrict__ b3,            // [K][O]
    float* __restrict__ out) {

    __shared__ unsigned short Hs[2][4][NB][8];   // 16 KB (8192 B per buffer)
    __shared__ f32x4 Gls4[OG * 625];             // 40 KB (k0..3), idx o*625+v*25+u
    __shared__ float Gls1[OG * 625];             // 10 KB (k4)
    __shared__ f32x4 W3km[K_ * OG * 16];         //  5 KB: [k][o][c], f32x4 over c
    __shared__ float biasS[NB];                  // 512 B

    const int tid = threadIdx.x;
    const int bid = blockIdx.x;
    const int obase = (bid & 15) * OG;
    const int n = bid >> 4;
    const int lane = tid & 63;
    const int wv_ = tid >> 6;

    // ---- stage Gls ----
    const size_t kstride = (size_t)N_ * O_ * 625;
    for (int i = tid; i < OG * 625; i += 512) {
        int o = i / 625, uv = i - o * 625;
        int u = uv / 25, v = uv - u * 25;
        size_t gb = ((size_t)n * O_ + obase + o) * 625 + uv;
        f32x4 g4;
        g4[0] = graphs[gb]               + Adj[uv];
        g4[1] = graphs[gb + kstride]     + Adj[625 + uv];
        g4[2] = graphs[gb + 2 * kstride] + Adj[1250 + uv];
        g4[3] = graphs[gb + 3 * kstride] + Adj[1875 + uv];
        int idx = o * 625 + v * 25 + u;
        Gls4[idx] = g4;
        Gls1[idx] = graphs[gb + 4 * kstride] + Adj[2500 + uv];
    }
    // ---- stage W3 k-major ----
    for (int i = tid; i < K_ * OG * C_; i += 512) {   // 1280 scalars
        int k = i / (OG * C_);
        int rem = i - k * (OG * C_);
        int o = rem >> 6, c = rem & 63;
        ((float*)W3km)[((k * OG + o) * C_) + c] = W3[((size_t)k * O_ + obase + o) * C_ + c];
    }
    __syncthreads();

    // ---- in-block bias ----
    if (tid < NB) {
        int o = tid >> 5, u = tid & 31;
        float bv = 0.f;
        if (u < U_) {
            f32x4 s4 = {0.f, 0.f, 0.f, 0.f};
            float s5 = 0.f;
            for (int v = 0; v < V_; ++v) {
                int idx = o * 625 + v * 25 + u;
                s4 += Gls4[idx];
                s5 += Gls1[idx];
            }
            bv = s4[0] * b3[0 * O_ + obase + o] + s4[1] * b3[1 * O_ + obase + o]
               + s4[2] * b3[2 * O_ + obase + o] + s4[3] * b3[3 * O_ + obase + o]
               + s5 * b3[4 * O_ + obase + o];
        }
        biasS[tid] = bv;
    }

    // ---- per-thread bases ----
    const int sl = wv_ & 3;
    const int hncol = (wv_ >> 2) * 64 + lane;   // 0..127
    const int ho = hncol >> 5;
    const int hu = hncol & 31;
    const int kw = OG * 16;                     // f32x4 stride per k in W3km
    const f32x4* wb  = &W3km[ho * 16 + sl * 2]; // parity -> +8 (static)
    const f32x4* gp4 = &Gls4[ho * 625 + hu];    // v -> +25*v
    const float* gp1 = &Gls1[ho * 625 + hu];
    uint4* hw = (uint4*)&Hs[0][sl][hncol][0];   // buf1 -> +512 uint4 (static)

    // h_form: parity/buffer static via pointer args; g passed in regs
    auto h_form = [&](uint4* hwp, const f32x4* wbp, f32x4 g, float g5) {
        f32x4 w0a = wbp[0],        w0b = wbp[1];
        f32x4 w1a = wbp[kw],       w1b = wbp[kw + 1];
        f32x4 w2a = wbp[2 * kw],   w2b = wbp[2 * kw + 1];
        f32x4 w3a = wbp[3 * kw],   w3b = wbp[3 * kw + 1];
        f32x4 w4a = wbp[4 * kw],   w4b = wbp[4 * kw + 1];
        float h[8];
#pragma unroll
        for (int j = 0; j < 4; ++j) {
            h[j]     = w0a[j] * g[0] + w1a[j] * g[1] + w2a[j] * g[2] + w3a[j] * g[3] + w4a[j] * g5;
            h[4 + j] = w0b[j] * g[0] + w1b[j] * g[1] + w2b[j] * g[2] + w3b[j] * g[3] + w4b[j] * g5;
        }
        uint4 hv;
        hv.x = cvtpk(h[0], h[1]); hv.y = cvtpk(h[2], h[3]);
        hv.z = cvtpk(h[4], h[5]); hv.w = cvtpk(h[6], h[7]);
        *hwp = hv;
    };
    auto ld_g = [&](int voff25, f32x4& g, float& g5) {
        if (hu < U_) { g = gp4[voff25]; g5 = gp1[voff25]; }
        else { g = (f32x4){0.f, 0.f, 0.f, 0.f}; g5 = 0.f; }
    };

    // ---- MFMA wave grid ----
    const int wm = wv_ >> 1;            // 0..3 -> t-base wm*64
    const int wn = wv_ & 1;             // 0..1 -> ncol-base wn*64
    const int lr = lane & 15;
    const int eg = lane >> 4;

    f32x4 acc[4][4];
#pragma unroll
    for (int mt = 0; mt < 4; ++mt)
#pragma unroll
        for (int nt = 0; nt < 4; ++nt) acc[mt][nt] = (f32x4){0.f, 0.f, 0.f, 0.f};

    const unsigned short* An = xT3 + (size_t)n * (T_ * CV);
    const unsigned short* a0 = An + ((size_t)((wm * 4 + 0) * 200 + eg)) * 128 + lr * 8;
    const unsigned short* a1 = a0 + 200 * 128;
    const unsigned short* a2 = a0 + 400 * 128;
    const unsigned short* a3 = a0 + 600 * 128;
    const char* hrb = (const char*)&Hs[0][eg][wn * 64 + lr][0];   // nt -> +256B, buf -> +8192B

    auto consume = [&](int sub /*elements: 0 or 512*/, int bufb /*bytes: 0 or 8192*/) {
        uint4 av0 = *(const uint4*)(a0 + sub);
        uint4 av1 = *(const uint4*)(a1 + sub);
        uint4 av2 = *(const uint4*)(a2 + sub);
        uint4 av3 = *(const uint4*)(a3 + sub);
        bf16x8 b[4];
#pragma unroll
        for (int nt = 0; nt < 4; ++nt)
            b[nt] = *(const bf16x8*)(hrb + bufb + nt * 256);
        __builtin_amdgcn_s_setprio(1);
        union { uint4 u; bf16x8 h; } c0, c1, c2, c3;
        c0.u = av0; c1.u = av1; c2.u = av2; c3.u = av3;
#pragma unroll
        for (int nt = 0; nt < 4; ++nt) acc[0][nt] = __builtin_amdgcn_mfma_f32_16x16x32_bf16(c0.h, b[nt], acc[0][nt], 0, 0, 0);
#pragma unroll
        for (int nt = 0; nt < 4; ++nt) acc[1][nt] = __builtin_amdgcn_mfma_f32_16x16x32_bf16(c1.h, b[nt], acc[1][nt], 0, 0, 0);
#pragma unroll
        for (int nt = 0; nt < 4; ++nt) acc[2][nt] = __builtin_amdgcn_mfma_f32_16x16x32_bf16(c2.h, b[nt], acc[2][nt], 0, 0, 0);
#pragma unroll
        for (int nt = 0; nt < 4; ++nt) acc[3][nt] = __builtin_amdgcn_mfma_f32_16x16x32_bf16(c3.h, b[nt], acc[3][nt], 0, 0, 0);
        __builtin_amdgcn_s_setprio(0);
    };

    // ---- prologue: form chunk 0 (v=0, par0) into buf0 ----
    f32x4 gv; float gv5;
    ld_g(0, gv, gv5);
    h_form(hw, wb, gv, gv5);
    __syncthreads();

    // ---- main loop: 25 pairs ----
    for (int kc2 = 0; kc2 < 25; ++kc2) {
        consume(0, 0);                          // chunk 2*kc2   (buf0, par0)
        h_form(hw + 512, wb + 8, gv, gv5);      // chunk 2*kc2+1 -> buf1, par1, same v
        __syncthreads();
        consume(512, 8192);                     // chunk 2*kc2+1 (buf1, par1)
        if (kc2 + 1 < 25) {
            ld_g((kc2 + 1) * 25, gv, gv5);
            h_form(hw, wb, gv, gv5);            // chunk 2*kc2+2 -> buf0, par0, v+1
        }
        __syncthreads();
        a0 += 1024; a1 += 1024; a2 += 1024; a3 += 1024;
    }

    // ---- epilogue: C/D col = lane&15 (ncol), row = eg*4 + r2 (t) ----
#pragma unroll
    for (int nt = 0; nt < 4; ++nt) {
        int ncol = wn * 64 + nt * 16 + lr;
        int ol = ncol >> 5;
        int u  = ncol & 31;
        if (u < U_) {
            float bv = biasS[ncol];
            float* ob = out + ((size_t)n * O_ + obase + ol) * T_ * V_ + u;
#pragma unroll
            for (int mt = 0; mt < 4; ++mt) {
                int t0 = wm * 64 + mt * 16 + eg * 4;
#pragma unroll
                for (int r2 = 0; r2 < 4; ++r2)
                    ob[(size_t)(t0 + r2) * V_] = acc[mt][nt][r2] + bv;
            }
        }
    }
}

// ---------------------------------------------------------------------------
// k_main_slow (fallback, proven R2 path)
// ---------------------------------------------------------------------------
#define OB 4
#define TB 64
__global__ __launch_bounds__(256, 1) void k_main_slow(
    const float* __restrict__ x, const float* __restrict__ graphs,
    const float* __restrict__ A, const float* __restrict__ W3,
    const float* __restrict__ b3, float* __restrict__ out) {
    int bid = blockIdx.x;
    int tb = bid & 3;
    int ob = (bid >> 2) & 15;
    int n  = bid >> 6;
    int tid = threadIdx.x;
    int ol = tid >> 6;
    int tl = tid & 63;
    int t = tb * TB + tl;
    int o = ob * OB + ol;

    __shared__ float Gs[K_][OB][V_][28];
    __shared__ float W3s[K_][OB][C_];
    __shared__ float b3s[K_][OB];

    for (int i = tid; i < K_ * OB * V_ * V_; i += 256) {
        int k   = i / (OB * V_ * V_);
        int rem = i % (OB * V_ * V_);
        int oo  = rem / (V_ * V_);
        int uv  = rem % (V_ * V_);
        Gs[k][oo][uv / V_][uv % V_] =
            graphs[(((size_t)k * N_ + n) * O_ + ob * OB + oo) * (V_ * V_) + uv]
            + A[k * V_ * V_ + uv];
    }
    for (int i = tid; i < K_ * OB * C_; i += 256) {
        int k   = i / (OB * C_);
        int rem = i % (OB * C_);
        int oo  = rem / C_, c = rem % C_;
        W3s[k][oo][c] = W3[((size_t)k * O_ + ob * OB + oo) * C_ + c];
    }
    if (tid < K_ * OB) b3s[tid / OB][tid % OB] = b3[(tid / OB) * O_ + ob * OB + tid % OB];
    __syncthreads();

    float x2[K_][V_];
#pragma unroll
    for (int k = 0; k < K_; ++k)
#pragma unroll
        for (int v = 0; v < V_; ++v) x2[k][v] = b3s[k][ol];

    const float* xb = x + ((size_t)n * C_ * T_ + t) * V_;
    for (int c = 0; c < C_; ++c) {
        const float* p = xb + (size_t)c * T_ * V_;
        float xv[V_];
#pragma unroll
        for (int v = 0; v < V_; ++v) xv[v] = p[v];
#pragma unroll
        for (int k = 0; k < K_; ++k) {
            float w = W3s[k][ol][c];
#pragma unroll
            for (int v = 0; v < V_; ++v) x2[k][v] += w * xv[v];
        }
    }

    float acc[V_];
#pragma unroll
    for (int u = 0; u < V_; ++u) acc[u] = 0.0f;
#pragma unroll
    for (int k = 0; k < K_; ++k) {
#pragma unroll
        for (int u = 0; u < V_; ++u) {
            const float* gr = &Gs[k][ol][u][0];
            float s = 0.0f;
#pragma unroll
            for (int v = 0; v < V_; ++v) s += gr[v] * x2[k][v];
            acc[u] += s;
        }
    }
    float* po = out + (((size_t)n * O_ + o) * T_ + t) * V_;
#pragma unroll
    for (int u = 0; u < V_; ++u) po[u] = acc[u];
}

// ---------------------------------------------------------------------------
extern "C" void kernel_launch(void* const* d_in, const int* in_sizes, int n_in,
                              void* d_out, int out_size, void* d_ws, size_t ws_size,
                              hipStream_t stream) {
    const float* x   = (const float*)d_in[0];
    const float* A   = (const float*)d_in[1];
    const float* W11 = (const float*)d_in[2];
    const float* b11 = (const float*)d_in[3];
    const float* W12 = (const float*)d_in[4];
    const float* b12 = (const float*)d_in[5];
    const float* W2  = (const float*)d_in[6];
    const float* b2  = (const float*)d_in[7];
    const float* W3  = (const float*)d_in[8];
    const float* b3  = (const float*)d_in[9];
    const float* W4  = (const float*)d_in[10];
    const float* b4  = (const float*)d_in[11];

    float* out    = (float*)d_out;
    float* graphs = out + OUT_ELEMS;   // second tuple element

    const size_t xT_bytes = sizeof(unsigned short) * (size_t)N_ * T_ * CV;  // 26.2 MB
    const size_t pp_bytes = sizeof(float) * (size_t)N_ * 16 * CV;           //  3.3 MB
    const size_t hdr      = (size_t)(1 << 20);
    const bool fast = (ws_size >= hdr + xT_bytes + pp_bytes);

    const size_t poolElems = (size_t)N_ * C_ * V_;      // 51,200
    const size_t tElems    = (size_t)K_ * N_ * R_ * V_; // 32,000
    const size_t slowNeed  = (poolElems + 2 * tElems) * sizeof(float);

    float* scratch = (fast || ws_size >= slowNeed) ? (float*)d_ws : out;
    float* pool = scratch;
    float* t2v  = scratch + poolElems;
    float* tSv  = t2v + tElems;
    unsigned short* xT3 = (unsigned short*)((char*)d_ws + hdr);
    float* pp = (float*)((char*)d_ws + hdr + xT_bytes);

    if (fast) {
        k_xcast   <<<N_ * 16, 256, 0, stream>>>(x, xT3, pp);
        k_graphs2c<<<K_ * N_ * 2, 512, 0, stream>>>(pp, W11, b11, W12, b12, W2, b2, W4, b4, graphs);
        k_main_fast<<<N_ * 16, 512, 0, stream>>>(xT3, graphs, A, W3, b3, out);
    } else {
        k_pool  <<<N_ * C_, 256, 0, stream>>>(x, pool);
        k_tvals <<<K_ * N_, 256, 0, stream>>>(pool, W11, b11, W12, b12, W2, b2, t2v, tSv);
        k_graphs<<<K_ * N_, 256, 0, stream>>>(t2v, tSv, W4, b4, graphs);
        k_main_slow<<<N_ * (O_ / OB) * 4, 256, 0, stream>>>(x, graphs, A, W3, b3, out);
    }
}